// Round 4
// baseline (313.194 us; speedup 1.0000x reference)
//
#include <hip/hip_runtime.h>

#define B_  2
#define T_  1024
#define D_  2048
#define NH  16
#define KH  4
#define HD  128
#define TC_ 1024
#define S_  2048

typedef __bf16 bf16x4v __attribute__((ext_vector_type(4)));
typedef __bf16 bf16x8v __attribute__((ext_vector_type(8)));
typedef float  f32x4v  __attribute__((ext_vector_type(4)));

__device__ __forceinline__ void async_copy16(void* lds, const void* g) {
    __builtin_amdgcn_global_load_lds(
        (__attribute__((address_space(1))) void*)g,
        (__attribute__((address_space(3))) void*)lds, 16, 0, 0);
}

// ---------------- x fp32 -> bf16 ----------------
__global__ void cvt_x(const float* __restrict__ x, __bf16* __restrict__ xb) {
    int i = (blockIdx.x * 256 + threadIdx.x) * 4;
    float4 v = *(const float4*)(x + i);
    bf16x4v o; o[0]=(__bf16)v.x; o[1]=(__bf16)v.y; o[2]=(__bf16)v.z; o[3]=(__bf16)v.w;
    *(bf16x4v*)(xb + i) = o;
}

// ---------------- weight transposes ----------------
__global__ void tp_w(const float* __restrict__ in, __bf16* __restrict__ out) {
    __shared__ float tile[32][33];
    int h0 = blockIdx.x * 32;
    int d0 = blockIdx.y * 32;
    const float* ip = in + (size_t)blockIdx.z * (D_ * HD);
    __bf16* op = out + (size_t)blockIdx.z * (D_ * HD);
    int tx = threadIdx.x, ty = threadIdx.y;
    for (int i = 0; i < 32; i += 8)
        tile[ty + i][tx] = ip[(size_t)(d0 + ty + i) * HD + h0 + tx];
    __syncthreads();
    for (int i = 0; i < 32; i += 8)
        op[(size_t)(h0 + ty + i) * D_ + d0 + tx] = (__bf16)tile[tx][ty + i];
}

__global__ void tp_wout(const float* __restrict__ in, __bf16* __restrict__ out) {
    __shared__ float tile[32][33];
    int d0 = blockIdx.x * 32;
    int h0 = blockIdx.y * 32;
    int n  = blockIdx.z;
    const float* ip = in + (size_t)n * (HD * D_);
    int tx = threadIdx.x, ty = threadIdx.y;
    for (int i = 0; i < 32; i += 8)
        tile[ty + i][tx] = ip[(size_t)(h0 + ty + i) * D_ + d0 + tx];
    __syncthreads();
    for (int i = 0; i < 32; i += 8)
        out[(size_t)(d0 + ty + i) * (NH * HD) + n * HD + h0 + tx] = (__bf16)tile[tx][ty + i];
}

// v out region fp32 [B][S][K][H] -> vtb bf16 [B][K][H][S]
__global__ void tp_v(const float* __restrict__ vout, __bf16* __restrict__ vtb) {
    __shared__ float tile[32][33];
    int z = blockIdx.z; int b = z / KH, kh = z % KH;
    int h0 = blockIdx.x * 32;
    int s0 = blockIdx.y * 32;
    const float* ip = vout + ((size_t)b * S_ * KH + kh) * HD;
    int tx = threadIdx.x, ty = threadIdx.y;
    for (int i = 0; i < 32; i += 8)
        tile[ty + i][tx] = ip[(size_t)(s0 + ty + i) * (KH * HD) + h0 + tx];
    __syncthreads();
    __bf16* op = vtb + ((size_t)b * KH + kh) * (size_t)HD * S_;
    for (int i = 0; i < 32; i += 8)
        op[(size_t)(h0 + ty + i) * S_ + s0 + tx] = (__bf16)tile[tx][ty + i];
}

// ---------------- cache copy (fp32 exact) + bf16 K-cache ----------------
__global__ void copy_cache(const float4* __restrict__ ck, const float4* __restrict__ cv,
                           float* __restrict__ kout, float* __restrict__ vout,
                           __bf16* __restrict__ kb) {
    int i = blockIdx.x * 256 + threadIdx.x;     // 262144 total
    int b = i >> 17;
    int r = i & 131071;
    float4 kv = ck[i];
    ((float4*)(kout + (size_t)b * S_ * KH * HD))[r] = kv;
    ((float4*)(vout + (size_t)b * S_ * KH * HD))[r] = cv[i];
    int h4 = r & 31;
    int kh = (r >> 5) & 3;
    int s  = r >> 7;
    bf16x4v o; o[0]=(__bf16)kv.x; o[1]=(__bf16)kv.y; o[2]=(__bf16)kv.z; o[3]=(__bf16)kv.w;
    *(bf16x4v*)(kb + (((size_t)(b * KH + kh) * S_ + s) * HD) + h4 * 4) = o;
}

// ---------------- generic 128x128-tile bf16 GEMM, C = A @ BT^T, K=2048 ----------------
__global__ __launch_bounds__(256, 2)
void gemm_bt(const __bf16* __restrict__ A, const __bf16* __restrict__ BT,
             float* __restrict__ C, int ldc) {
    __shared__ __bf16 As[128 * 64];
    __shared__ __bf16 Bs[128 * 64];
    const int m0 = blockIdx.x * 128, n0 = blockIdx.y * 128;
    const int tid = threadIdx.x;
    const int wave = tid >> 6, lane = tid & 63;
    const int quad = lane >> 4, l16 = lane & 15;
    const int wm = (wave & 1) * 64, wn = (wave >> 1) * 64;
    const int lrow = lane >> 3, lcol = (lane & 7) * 8;

    f32x4v acc[4][4];
    for (int i = 0; i < 4; i++)
        for (int j = 0; j < 4; j++)
            acc[i][j] = (f32x4v){0.f, 0.f, 0.f, 0.f};

    const __bf16* Abase = A + (size_t)m0 * D_;
    const __bf16* Bbase = BT + (size_t)n0 * D_;

    for (int k0 = 0; k0 < D_; k0 += 64) {
        for (int j = 0; j < 4; j++) {
            int r = wave * 32 + j * 8;
            async_copy16(As + (size_t)r * 64,
                         Abase + (size_t)(r + lrow) * D_ + k0 + lcol);
            async_copy16(Bs + (size_t)r * 64,
                         Bbase + (size_t)(r + lrow) * D_ + k0 + lcol);
        }
        __syncthreads();
        for (int ks = 0; ks < 2; ks++) {
            bf16x8v a[4], b[4];
            for (int i = 0; i < 4; i++)
                a[i] = *(const bf16x8v*)(As + (wm + i * 16 + l16) * 64 + ks * 32 + quad * 8);
            for (int j = 0; j < 4; j++)
                b[j] = *(const bf16x8v*)(Bs + (wn + j * 16 + l16) * 64 + ks * 32 + quad * 8);
            for (int i = 0; i < 4; i++)
                for (int j = 0; j < 4; j++)
                    acc[i][j] = __builtin_amdgcn_mfma_f32_16x16x32_bf16(a[i], b[j], acc[i][j], 0, 0, 0);
        }
        __syncthreads();
    }
    for (int i = 0; i < 4; i++)
        for (int j = 0; j < 4; j++)
            for (int r = 0; r < 4; r++) {
                int row = m0 + wm + i * 16 + quad * 4 + r;
                int col = n0 + wn + j * 16 + l16;
                C[(size_t)row * ldc + col] = acc[i][j][r];
            }
}

// ---------------- RoPE + scatter QKV (+ bf16 new-K) ----------------
__global__ void finish_rope(const float* __restrict__ proj, const int* __restrict__ pos,
                            __bf16* __restrict__ qws, float* __restrict__ kout,
                            float* __restrict__ vout, __bf16* __restrict__ kb) {
    const int tau = blockIdx.x;
    const int b = tau >> 10, t = tau & 1023;
    const float p = (float)pos[tau];
    const float* pr = proj + (size_t)tau * 3072;
    const float qscale = 0.08838834764831845f;   // 128^-0.5
    for (int idx = threadIdx.x; idx < (NH + KH) * 64; idx += 256) {
        int head = idx >> 6;
        int hh = idx & 63;
        float r = p * __expf(-(float)hh * (9.210340371976184f / 64.0f));
        float sn = sinf(r), cs = cosf(r);
        if (head < NH) {
            float x1 = pr[head * HD + hh], x2 = pr[head * HD + hh + 64];
            size_t qo = ((size_t)tau * NH + head) * HD;
            qws[qo + hh]      = (__bf16)((x1 * cs - x2 * sn) * qscale);
            qws[qo + hh + 64] = (__bf16)((x2 * cs + x1 * sn) * qscale);
        } else {
            int kh = head - NH;
            float x1 = pr[2048 + kh * HD + hh], x2 = pr[2048 + kh * HD + hh + 64];
            float k1 = x1 * cs - x2 * sn, k2 = x2 * cs + x1 * sn;
            size_t ko = ((size_t)(b * S_ + TC_ + t) * KH + kh) * HD;
            kout[ko + hh]      = k1;
            kout[ko + hh + 64] = k2;
            size_t kbo = ((size_t)(b * KH + kh) * S_ + TC_ + t) * HD;
            kb[kbo + hh]      = (__bf16)k1;
            kb[kbo + hh + 64] = (__bf16)k2;
        }
    }
    for (int idx = threadIdx.x; idx < KH * HD; idx += 256) {
        int kh = idx >> 7, h = idx & 127;
        vout[((size_t)(b * S_ + TC_ + t) * KH + kh) * HD + h] = pr[2560 + kh * HD + h];
    }
}

// ---------------- flash attention: 4 waves x 32 q-rows, S-tile 64, split-S halves ----------------
// Q frags in registers (loaded once). LDS: Ks 16K + Vs 16K + Ps(stride 72) 18K = 50KB -> 2 blocks/CU.
// Each block does one half of the S-range; unnormalized O + (m,l) partials merged by `merge`.
__global__ __launch_bounds__(256, 2)
void attn(const __bf16* __restrict__ qws, const __bf16* __restrict__ kb,
          const __bf16* __restrict__ vtb,
          __bf16* __restrict__ op0, __bf16* __restrict__ op1,
          float2* __restrict__ mlb0, float2* __restrict__ mlb1) {
    __shared__ __bf16 Ks[64 * 128];
    __shared__ __bf16 Vs[128 * 64];
    __shared__ __bf16 Ps[128 * 72];

    const int t0 = blockIdx.x * 128;
    const int n  = blockIdx.y;
    const int bz = blockIdx.z;
    const int b = bz >> 1, half = bz & 1;
    const int kh = n >> 2;                 // NH/KH = 4
    const int tid = threadIdx.x, w = tid >> 6, lane = tid & 63;
    const int quad = lane >> 4, l16 = lane & 15;

    // Q fragments in registers: wave w owns q-rows [w*32, w*32+32)
    bf16x8v qf[2][4];
    {
        const __bf16* qbase = qws + ((size_t)(b * T_ + t0 + w * 32) * NH + n) * HD;
        for (int qt = 0; qt < 2; qt++)
            for (int ks = 0; ks < 4; ks++)
                qf[qt][ks] = *(const bf16x8v*)(qbase + (size_t)(qt * 16 + l16) * (NH * HD)
                                               + ks * 32 + quad * 8);
    }

    float m_run[2][4], l_run[2][4];
    f32x4v o_acc[2][8];
    for (int qt = 0; qt < 2; qt++)
        for (int r = 0; r < 4; r++) { m_run[qt][r] = -INFINITY; l_run[qt][r] = 0.f; }
    for (int qt = 0; qt < 2; qt++)
        for (int j = 0; j < 8; j++) o_acc[qt][j] = (f32x4v){0.f, 0.f, 0.f, 0.f};

    const int nS  = (TC_ + t0 + 128) >> 6;         // S-tiles of 64; always even
    const int st0 = half ? (nS >> 1) : 0;
    const int st1 = half ? nS : (nS >> 1);
    const int wk_max = TC_ + t0 + w * 32 + 31;     // max key this wave can see
    const __bf16* kbase = kb  + ((size_t)(b * KH + kh)) * S_ * HD;
    const __bf16* vbase = vtb + ((size_t)(b * KH + kh)) * (size_t)HD * S_;

    for (int st = st0; st < st1; st++) {
        const int s0 = st * 64;
        // stage K [64 s][128 h], chunk-swizzled ^(row&15)
        {
            const int ar = lane >> 4, ac = lane & 15;
            for (int jj = 0; jj < 4; jj++) {
                int r0 = w * 16 + jj * 4;
                int row = r0 + ar;
                async_copy16(Ks + (size_t)r0 * 128,
                             kbase + (size_t)(s0 + row) * HD + ((ac ^ (row & 15)) * 8));
            }
        }
        // stage V^T [128 h][64 s], chunk-swizzled ^(row&7)
        {
            const int ar = lane >> 3, ac = lane & 7;
            for (int jj = 0; jj < 4; jj++) {
                int r0 = w * 32 + jj * 8;
                int row = r0 + ar;
                async_copy16(Vs + (size_t)r0 * 64,
                             vbase + (size_t)row * S_ + s0 + ((ac ^ (row & 7)) * 8));
            }
        }
        __syncthreads();

        if (s0 <= wk_max) {   // wave-uniform; skip fully-masked tail tiles
            // QK^T: 32 q-rows x 64 s-cols
            f32x4v sc[2][4];
            for (int qt = 0; qt < 2; qt++)
                for (int j = 0; j < 4; j++) sc[qt][j] = (f32x4v){0.f, 0.f, 0.f, 0.f};
            for (int ks = 0; ks < 4; ks++) {
                bf16x8v bb[4];
                for (int j = 0; j < 4; j++)
                    bb[j] = *(const bf16x8v*)(Ks + (j * 16 + l16) * 128
                                              + (((ks * 4 + quad) ^ l16) * 8));
                for (int qt = 0; qt < 2; qt++)
                    for (int j = 0; j < 4; j++)
                        sc[qt][j] = __builtin_amdgcn_mfma_f32_16x16x32_bf16(qf[qt][ks], bb[j], sc[qt][j], 0, 0, 0);
            }

            // causal mask (only last 2 tiles can touch the diagonal)
            if (st >= nS - 2) {
                for (int qt = 0; qt < 2; qt++)
                    for (int j = 0; j < 4; j++)
                        for (int r = 0; r < 4; r++) {
                            int s_abs = s0 + j * 16 + l16;
                            int q_abs = t0 + w * 32 + qt * 16 + quad * 4 + r;
                            if (s_abs > TC_ + q_abs) sc[qt][j][r] = -3.0e38f;
                        }
            }

            // online softmax (row lives in 16 l16-lanes of this quad)
            for (int qt = 0; qt < 2; qt++)
                for (int r = 0; r < 4; r++) {
                    float mx = sc[qt][0][r];
                    for (int j = 1; j < 4; j++) mx = fmaxf(mx, sc[qt][j][r]);
                    for (int off = 8; off >= 1; off >>= 1) mx = fmaxf(mx, __shfl_xor(mx, off, 64));
                    mx = fmaxf(mx, m_run[qt][r]);
                    float alpha = __expf(m_run[qt][r] - mx);
                    m_run[qt][r] = mx;
                    float s = 0.f;
                    for (int j = 0; j < 4; j++) {
                        float pv = __expf(sc[qt][j][r] - mx);
                        sc[qt][j][r] = pv;
                        s += pv;
                    }
                    for (int off = 8; off >= 1; off >>= 1) s += __shfl_xor(s, off, 64);
                    l_run[qt][r] = l_run[qt][r] * alpha + s;
                    for (int j = 0; j < 8; j++) o_acc[qt][j][r] *= alpha;
                }

            // P -> LDS (wave-local rows; stride 72 keeps 16B alignment, ~4-way writes)
            for (int qt = 0; qt < 2; qt++)
                for (int j = 0; j < 4; j++)
                    for (int r = 0; r < 4; r++) {
                        int row = w * 32 + qt * 16 + quad * 4 + r;
                        Ps[row * 72 + j * 16 + l16] = (__bf16)sc[qt][j][r];
                    }
            // no barrier needed: PV reads only this wave's own P rows

            // PV: o_acc += P @ V  (contraction over 64 s)
            for (int ks = 0; ks < 2; ks++) {
                bf16x8v av[2];
                for (int qt = 0; qt < 2; qt++)
                    av[qt] = *(const bf16x8v*)(Ps + (w * 32 + qt * 16 + l16) * 72
                                               + ks * 32 + quad * 8);
                bf16x8v bb[8];
                for (int j = 0; j < 8; j++)
                    bb[j] = *(const bf16x8v*)(Vs + (j * 16 + l16) * 64
                                              + (((ks * 4 + quad) ^ (l16 & 7)) * 8));
                for (int qt = 0; qt < 2; qt++)
                    for (int j = 0; j < 8; j++)
                        o_acc[qt][j] = __builtin_amdgcn_mfma_f32_16x16x32_bf16(av[qt], bb[j], o_acc[qt][j], 0, 0, 0);
            }
        }
        __syncthreads();   // protect Ks/Vs before next staging
    }

    // epilogue: unnormalized O + (m,l) partials
    __bf16* op = half ? op1 : op0;
    float2* ml = half ? mlb1 : mlb0;
    for (int qt = 0; qt < 2; qt++)
        for (int r = 0; r < 4; r++) {
            int grow = (b * NH + n) * T_ + t0 + w * 32 + qt * 16 + quad * 4 + r;
            if (l16 == 0) ml[grow] = make_float2(m_run[qt][r], l_run[qt][r]);
            for (int j = 0; j < 8; j++)
                op[(size_t)grow * HD + j * 16 + l16] = (__bf16)o_acc[qt][j][r];
        }
}

// ---------------- merge split-S partials -> enc bf16 [b,t,n,h] ----------------
__global__ void merge(const __bf16* __restrict__ o0, const __bf16* __restrict__ o1,
                      const float2* __restrict__ ml0, const float2* __restrict__ ml1,
                      __bf16* __restrict__ enc) {
    int gid = blockIdx.x * 256 + threadIdx.x;   // B*NH*T*HD/4 = 1048576
    int row = gid >> 5, c4 = (gid & 31) * 4;
    float2 A = ml0[row], Bm = ml1[row];
    float m  = fmaxf(A.x, Bm.x);
    float wA = __expf(A.x - m), wB = __expf(Bm.x - m);
    float inv = 1.0f / (wA * A.y + wB * Bm.y);
    bf16x4v a = *(const bf16x4v*)(o0 + (size_t)row * HD + c4);
    bf16x4v c = *(const bf16x4v*)(o1 + (size_t)row * HD + c4);
    int b = row >> 14, n = (row >> 10) & 15, t = row & 1023;
    bf16x4v e;
    for (int i = 0; i < 4; i++)
        e[i] = (__bf16)((wA * (float)a[i] + wB * (float)c[i]) * inv);
    *(bf16x4v*)(enc + (((size_t)(b * T_ + t) * NH + n) * HD) + c4) = e;
}

extern "C" void kernel_launch(void* const* d_in, const int* in_sizes, int n_in,
                              void* d_out, int out_size, void* d_ws, size_t ws_size,
                              hipStream_t stream) {
    const float* x       = (const float*)d_in[0];
    const int*   pos     = (const int*)d_in[1];
    const float* cache_k = (const float*)d_in[3];
    const float* cache_v = (const float*)d_in[4];
    const float* w_q     = (const float*)d_in[5];
    const float* w_kv    = (const float*)d_in[6];
    const float* w_out   = (const float*)d_in[7];

    float* out  = (float*)d_out;
    float* kout = out  + (size_t)B_ * T_ * D_;
    float* vout = kout + (size_t)B_ * S_ * KH * HD;

    char* ws = (char*)d_ws;
    __bf16* xb   = (__bf16*)ws;  ws += (size_t)B_ * T_ * D_ * 2;
    __bf16* wt   = (__bf16*)ws;  ws += (size_t)3072 * D_ * 2;
    __bf16* wot  = (__bf16*)ws;  ws += (size_t)D_ * NH * HD * 2;
    float*  proj = (float*)ws;   ws += (size_t)B_ * T_ * 3072 * 4;
    __bf16* qws  = (__bf16*)ws;  ws += (size_t)B_ * T_ * NH * HD * 2;
    __bf16* kbuf = (__bf16*)ws;  ws += (size_t)B_ * S_ * KH * HD * 2;
    __bf16* vtb  = (__bf16*)ws;  ws += (size_t)B_ * S_ * KH * HD * 2;
    __bf16* enc  = (__bf16*)ws;

    // attn partials alias the (dead-after-finish_rope) proj region: 17.3 MB < 25.2 MB
    const size_t ON = (size_t)B_ * NH * T_ * HD;      // 4,194,304
    __bf16* op0 = (__bf16*)proj;
    __bf16* op1 = op0 + ON;
    float2* ml0 = (float2*)(op1 + ON);
    float2* ml1 = ml0 + (size_t)B_ * NH * T_;

    cvt_x<<<4096, 256, 0, stream>>>(x, xb);
    tp_w<<<dim3(4, 64, 16), dim3(32, 8), 0, stream>>>(w_q, wt);
    tp_w<<<dim3(4, 64, 8),  dim3(32, 8), 0, stream>>>(w_kv, wt + (size_t)16 * HD * D_);
    tp_wout<<<dim3(64, 4, 16), dim3(32, 8), 0, stream>>>(w_out, wot);
    copy_cache<<<1024, 256, 0, stream>>>((const float4*)cache_k, (const float4*)cache_v, kout, vout, kbuf);
    gemm_bt<<<dim3(16, 24), 256, 0, stream>>>(xb, wt, proj, 3072);
    finish_rope<<<2048, 256, 0, stream>>>(proj, pos, qws, kout, vout, kbuf);
    tp_v<<<dim3(4, 64, 8), dim3(32, 8), 0, stream>>>(vout, vtb);
    attn<<<dim3(8, 16, 4), 256, 0, stream>>>(qws, kbuf, vtb, op0, op1, ml0, ml1);
    merge<<<4096, 256, 0, stream>>>(op0, op1, ml0, ml1, enc);
    gemm_bt<<<dim3(16, 16), 256, 0, stream>>>(enc, wot, out, 2048);
}